// Round 1
// baseline (211.485 us; speedup 1.0000x reference)
//
#include <hip/hip_runtime.h>

#define Bq 2
#define Nq 1024
#define Cq 128
#define Eq 64
#define Kq 20

// ---------------- Kernel A: x @ Wl + bl and x @ Wr + br ----------------
// grid = B*N rows, block = 128 threads. Threads 0..63 compute x_l[row][e],
// threads 64..127 compute x_r[row][e-64].
__global__ __launch_bounds__(128) void proj_kernel(
    const float* __restrict__ x, const float* __restrict__ Wl,
    const float* __restrict__ bl, const float* __restrict__ Wr,
    const float* __restrict__ br, float* __restrict__ xl,
    float* __restrict__ xr) {
  int row = blockIdx.x;
  int t = threadIdx.x;
  __shared__ float xs[Cq];
  xs[t] = x[(size_t)row * Cq + t];
  __syncthreads();
  const float* W    = (t < Eq) ? Wl : Wr;
  const float* bias = (t < Eq) ? bl : br;
  float* outp       = (t < Eq) ? xl : xr;
  int e = t & (Eq - 1);
  float acc = 0.f;
#pragma unroll 8
  for (int c = 0; c < Cq; ++c) acc += xs[c] * W[c * Eq + e];
  outp[(size_t)row * Eq + e] = acc + bias[e];
}

// ---------------- Kernel B: scores + top-K + softmax + outputs ----------------
// One block per (b,i): 256 threads = 4 waves. Lane d owns dim d (E=64 == wave).
__global__ __launch_bounds__(256) void attn_kernel(
    const float* __restrict__ xl, const float* __restrict__ xr,
    const float* __restrict__ att, float* __restrict__ out) {
  const int gi   = blockIdx.x;      // b*N + i; equals index_i value directly
  const int b    = gi >> 10;        // N = 1024
  const int tid  = threadIdx.x;
  const int lane = tid & 63;
  const int wave = tid >> 6;        // 0..3

  __shared__ float alpha[Nq];
  __shared__ float xls[Eq];
  __shared__ float atts[Eq];
  __shared__ float topv[Kq];
  __shared__ int   topi[Kq];
  __shared__ float redv[4];
  __shared__ int   redi[4];

  if (tid < Eq) {
    xls[tid]  = xl[(size_t)gi * Eq + tid];
    atts[tid] = att[tid];
  }
  __syncthreads();

  const float xld = xls[lane];
  const float ad  = atts[lane];
  const float* __restrict__ xrb = xr + (size_t)b * Nq * Eq;

  // ---- alpha[j] for all j: each wave handles j = 4*t + wave ----
  for (int t = 0; t < Nq / 4; ++t) {
    const int j = t * 4 + wave;
    float v = xld + xrb[(size_t)j * Eq + lane];
    v = (v > 0.f) ? v : 0.2f * v;   // leaky_relu slope 0.2
    v *= ad;
#pragma unroll
    for (int m = 1; m < 64; m <<= 1) v += __shfl_xor(v, m);
    if (lane == 0) alpha[j] = v;
  }
  __syncthreads();

  // ---- iterative top-K extraction (descending, ties -> lower index) ----
  for (int sel = 0; sel < Kq; ++sel) {
    float bv = -3.4e38f;
    int   bi = 1 << 30;
    for (int t = tid; t < Nq; t += 256) {      // ascending scan keeps lower idx on tie
      float v = alpha[t];
      if (v > bv) { bv = v; bi = t; }
    }
#pragma unroll
    for (int m = 1; m < 64; m <<= 1) {
      float ov = __shfl_xor(bv, m);
      int   oi = __shfl_xor(bi, m);
      if (ov > bv || (ov == bv && oi < bi)) { bv = ov; bi = oi; }
    }
    if (lane == 0) { redv[wave] = bv; redi[wave] = bi; }
    __syncthreads();
    if (tid == 0) {
      for (int w = 1; w < 4; ++w)
        if (redv[w] > bv || (redv[w] == bv && redi[w] < bi)) { bv = redv[w]; bi = redi[w]; }
      topv[sel] = bv;
      topi[sel] = bi;
      alpha[bi] = -3.4e38f;   // knock out for next extraction
    }
    __syncthreads();
  }

  // ---- softmax over the K values + write all three output segments ----
  if (tid < 64) {
    float p = (tid < Kq) ? expf(topv[tid] - topv[0]) : 0.f;
    float s = p;
#pragma unroll
    for (int m = 1; m < 64; m <<= 1) s += __shfl_xor(s, m);
    if (tid < Kq) {
      const int base = gi * Kq + tid;
      out[base]                   = (float)gi;                   // index_i
      out[Bq * Nq * Kq + base]    = (float)(topi[tid] + b * Nq); // index_j
      out[2 * Bq * Nq * Kq + base] = p / s;                      // attention
    }
  }
}

extern "C" void kernel_launch(void* const* d_in, const int* in_sizes, int n_in,
                              void* d_out, int out_size, void* d_ws, size_t ws_size,
                              hipStream_t stream) {
  const float* x   = (const float*)d_in[0];
  const float* Wl  = (const float*)d_in[1];
  const float* bl  = (const float*)d_in[2];
  const float* Wr  = (const float*)d_in[3];
  const float* br  = (const float*)d_in[4];
  const float* att = (const float*)d_in[5];
  float* out = (float*)d_out;

  float* xl = (float*)d_ws;                    // [B*N, E]
  float* xr = xl + (size_t)Bq * Nq * Eq;       // [B*N, E]

  proj_kernel<<<Bq * Nq, Cq, 0, stream>>>(x, Wl, bl, Wr, br, xl, xr);
  attn_kernel<<<Bq * Nq, 256, 0, stream>>>(xl, xr, att, out);
}

// Round 2
// 42.534 us; speedup vs baseline: 4.9722x; 4.9722x over previous
//
#include <hip/hip_runtime.h>

#define Bq 2
#define Nq 1024
#define Cq 128
#define Eq 64
#define Kq 20
#define TI 8          // rows i per attn block
#define THREADS 512   // 8 waves: wave w owns row w in phase 2

// ---------------- Kernel A: projections + rdot, xr stored transposed ----------------
// grid = B*N, block = 128. Threads 0..63 -> x_l row, threads 64..127 -> x_r row.
__global__ __launch_bounds__(128) void proj_kernel(
    const float* __restrict__ x, const float* __restrict__ Wl,
    const float* __restrict__ bl, const float* __restrict__ Wr,
    const float* __restrict__ br, const float* __restrict__ att,
    float* __restrict__ xl, float* __restrict__ xrT, float* __restrict__ rdot) {
  const int row = blockIdx.x;
  const int t = threadIdx.x;
  __shared__ float xs[Cq];
  xs[t] = x[(size_t)row * Cq + t];
  __syncthreads();
  const float* W = (t < Eq) ? Wl : Wr;
  const int e = t & 63;
  float acc = 0.f;
#pragma unroll 8
  for (int c = 0; c < Cq; ++c) acc += xs[c] * W[c * Eq + e];
  acc += (t < Eq) ? bl[e] : br[e];
  if (t < Eq) {
    xl[(size_t)row * Eq + e] = acc;
  } else {
    xrT[(size_t)e * (Bq * Nq) + row] = acc;   // transposed: [d][B*N]
    float rd = acc * att[e];                  // wave 1 reduce -> rdot[row]
#pragma unroll
    for (int m = 1; m < 64; m <<= 1) rd += __shfl_xor(rd, m);
    if (e == 0) rdot[row] = rd;
  }
}

// ---------------- Kernel B: alpha (8 rows/block) + in-register top-K ----------------
__global__ __launch_bounds__(THREADS) void attn_kernel(
    const float* __restrict__ xl, const float* __restrict__ xrT,
    const float* __restrict__ rdot, const float* __restrict__ att,
    float* __restrict__ out) {
  const int gi0  = blockIdx.x * TI;   // global row base (TI divides N: no batch straddle)
  const int b    = gi0 >> 10;
  const int tid  = threadIdx.x;
  const int lane = tid & 63;
  const int wave = tid >> 6;

  __shared__ float alpha[TI][Nq];
  __shared__ float xls[TI][Eq];
  __shared__ float catt[Eq];

  // stage xl rows (512 floats, one per thread) + 0.4*att
  xls[tid >> 6][tid & 63] = xl[(size_t)gi0 * Eq + tid];
  if (tid < Eq) catt[tid] = 0.4f * att[tid];
  __syncthreads();

  // ---- phase 1: alpha[r][j], thread owns j = 2*tid, 2*tid+1 ----
  {
    const int j = tid * 2;
    const float2 rd = *(const float2*)&rdot[b * Nq + j];
    float acc[TI][2];
#pragma unroll
    for (int r = 0; r < TI; ++r) { acc[r][0] = 0.6f * rd.x; acc[r][1] = 0.6f * rd.y; }
    const float* __restrict__ xrb = xrT + (size_t)b * Nq + j;
#pragma unroll
    for (int ch = 0; ch < 16; ++ch) {
      const float4 cv = *(const float4*)&catt[ch * 4];
      float4 xlv[TI];
#pragma unroll
      for (int r = 0; r < TI; ++r) xlv[r] = *(const float4*)&xls[r][ch * 4];
#pragma unroll
      for (int dd = 0; dd < 4; ++dd) {
        const float2 xv = *(const float2*)&xrb[(size_t)(ch * 4 + dd) * (Bq * Nq)];
        const float c = ((const float*)&cv)[dd];
#pragma unroll
        for (int r = 0; r < TI; ++r) {
          const float xld = ((const float*)&xlv[r])[dd];
          acc[r][0] = fmaf(fabsf(xld + xv.x), c, acc[r][0]);
          acc[r][1] = fmaf(fabsf(xld + xv.y), c, acc[r][1]);
        }
      }
    }
#pragma unroll
    for (int r = 0; r < TI; ++r)
      *(float2*)&alpha[r][j] = make_float2(acc[r][0], acc[r][1]);
  }
  __syncthreads();

  // ---- phase 2: wave w does top-K of row w, barrier-free, in registers ----
  const int r = wave;
  float vals[16];
#pragma unroll
  for (int s = 0; s < 16; ++s) vals[s] = alpha[r][lane + 64 * s];  // j = lane + 64*s
  float lv = -3.4e38f; int li = 0;
#pragma unroll
  for (int s = 0; s < 16; ++s) if (vals[s] > lv) { lv = vals[s]; li = s; }

  float m0 = 0.f, ssum = 0.f, myv = 0.f;
  int myi = 0;
  for (int round = 0; round < Kq; ++round) {
    float bv = lv;
    int   bi = (li << 6) | lane;          // bi == j (= 64*s + lane)
#pragma unroll
    for (int mm = 1; mm < 64; mm <<= 1) {
      const float ov = __shfl_xor(bv, mm);
      const int   oi = __shfl_xor(bi, mm);
      if (ov > bv || (ov == bv && oi < bi)) { bv = ov; bi = oi; }
    }
    if (round == 0) m0 = bv;
    ssum += __expf(bv - m0);              // uniform across lanes
    if (lane == round) { myv = bv; myi = bi; }
    if ((bi & 63) == lane) {              // owner knocks out its winning element
#pragma unroll
      for (int s = 0; s < 16; ++s) vals[s] = (s == li) ? -3.4e38f : vals[s];
      lv = -3.4e38f; li = 0;
#pragma unroll
      for (int s = 0; s < 16; ++s) if (vals[s] > lv) { lv = vals[s]; li = s; }
    }
  }

  if (lane < Kq) {
    const int gi = gi0 + r;
    const float p = __expf(myv - m0) / ssum;
    const int base = gi * Kq + lane;
    out[base]                    = (float)gi;            // index_i
    out[Bq * Nq * Kq + base]     = (float)(b * Nq + myi);// index_j
    out[2 * Bq * Nq * Kq + base] = p;                    // attention
  }
}

extern "C" void kernel_launch(void* const* d_in, const int* in_sizes, int n_in,
                              void* d_out, int out_size, void* d_ws, size_t ws_size,
                              hipStream_t stream) {
  const float* x   = (const float*)d_in[0];
  const float* Wl  = (const float*)d_in[1];
  const float* bl  = (const float*)d_in[2];
  const float* Wr  = (const float*)d_in[3];
  const float* br  = (const float*)d_in[4];
  const float* att = (const float*)d_in[5];
  float* out = (float*)d_out;

  float* xl   = (float*)d_ws;                       // [B*N, E]
  float* xrT  = xl + (size_t)Bq * Nq * Eq;          // [E, B*N] transposed
  float* rdot = xrT + (size_t)Eq * Bq * Nq;         // [B*N]

  proj_kernel<<<Bq * Nq, Cq, 0, stream>>>(x, Wl, bl, Wr, br, att, xl, xrT, rdot);
  attn_kernel<<<(Bq * Nq) / TI, THREADS, 0, stream>>>(xl, xrT, rdot, att, out);
}

// Round 3
// 41.286 us; speedup vs baseline: 5.1224x; 1.0302x over previous
//
#include <hip/hip_runtime.h>

#define Bq 2
#define Nq 1024
#define Cq 128
#define Eq 64
#define Kq 20
#define TI 8
#define BNK (Bq * Nq * Kq)
#define NEGF (-3.0e38f)

// DPP shuffles (VALU pipe, no LDS): quad_perm xor1/xor2, row_ror 4/8
#define DPP_F(x, ctrl) __int_as_float(__builtin_amdgcn_update_dpp( \
    __float_as_int(x), __float_as_int(x), (ctrl), 0xf, 0xf, false))
#define DPP_I(x, ctrl) __builtin_amdgcn_update_dpp((x), (x), (ctrl), 0xf, 0xf, false)
#define RL_F(x, l) __int_as_float(__builtin_amdgcn_readlane(__float_as_int(x), (l)))
#define RL_I(x, l) __builtin_amdgcn_readlane((x), (l))
#define QP_XOR1 0xB1   // quad_perm [1,0,3,2]
#define QP_XOR2 0x4E   // quad_perm [2,3,0,1]
#define ROR4    0x124  // row_ror:4
#define ROR8    0x128  // row_ror:8

// ---------------- Kernel A: projections + rdot; x via scalar loads ----------------
// grid = (B*N)/4 blocks, block = 128. Lanes 0..63 (wave 0) -> Wl, 64..127 -> Wr.
__global__ __launch_bounds__(128) void proj_kernel(
    const float* __restrict__ x, const float* __restrict__ Wl,
    const float* __restrict__ bl, const float* __restrict__ Wr,
    const float* __restrict__ br, const float* __restrict__ att,
    float* __restrict__ xl, float* __restrict__ xrT, float* __restrict__ rdot) {
  const int r0 = blockIdx.x * 4;           // 4 rows per block
  const int t = threadIdx.x;
  const int e = t & 63;
  const bool left = (t < 64);
  const float* __restrict__ W = left ? Wl : Wr;
  const float* __restrict__ xrow = x + (size_t)r0 * Cq;  // block-uniform -> s_load

  float acc[4] = {0.f, 0.f, 0.f, 0.f};
#pragma unroll 8
  for (int c4 = 0; c4 < Cq / 4; ++c4) {
    const float4 xa = *(const float4*)&xrow[c4 * 4];
    const float4 xb = *(const float4*)&xrow[Cq + c4 * 4];
    const float4 xc = *(const float4*)&xrow[2 * Cq + c4 * 4];
    const float4 xd = *(const float4*)&xrow[3 * Cq + c4 * 4];
    const float a0[4] = {xa.x, xa.y, xa.z, xa.w};
    const float a1[4] = {xb.x, xb.y, xb.z, xb.w};
    const float a2[4] = {xc.x, xc.y, xc.z, xc.w};
    const float a3[4] = {xd.x, xd.y, xd.z, xd.w};
#pragma unroll
    for (int dd = 0; dd < 4; ++dd) {
      const float w = W[(c4 * 4 + dd) * Eq + e];
      acc[0] = fmaf(a0[dd], w, acc[0]);
      acc[1] = fmaf(a1[dd], w, acc[1]);
      acc[2] = fmaf(a2[dd], w, acc[2]);
      acc[3] = fmaf(a3[dd], w, acc[3]);
    }
  }
  const float bias = left ? bl[e] : br[e];
#pragma unroll
  for (int k = 0; k < 4; ++k) acc[k] += bias;

  if (left) {
#pragma unroll
    for (int k = 0; k < 4; ++k) xl[(size_t)(r0 + k) * Eq + e] = acc[k];
  } else {
    const float ae = att[e];
#pragma unroll
    for (int k = 0; k < 4; ++k) {
      xrT[(size_t)e * (Bq * Nq) + r0 + k] = acc[k];
      float s = acc[k] * ae;                     // rdot[row] = sum_e xr*att
      s += DPP_F(s, QP_XOR1);
      s += DPP_F(s, QP_XOR2);
      s += DPP_F(s, ROR4);
      s += DPP_F(s, ROR8);
      const float sd = (RL_F(s, 0) + RL_F(s, 16)) + (RL_F(s, 32) + RL_F(s, 48));
      if (e == 0) rdot[r0 + k] = sd;
    }
  }
}

// ---------------- Kernel B: scores (8 rows/block) + DPP top-K + softmax ----------------
// block = 512 (8 waves). Phase 1: thread = (rgroup of 4 rows) x (4 consecutive j).
// Phase 2: wave w owns row w; all cross-lane via DPP/readlane, zero LDS shuffles.
__global__ __launch_bounds__(512) void attn_kernel(
    const float* __restrict__ xl, const float* __restrict__ xrT,
    const float* __restrict__ rdot, const float* __restrict__ att,
    float* __restrict__ out) {
  const int gi0  = blockIdx.x * TI;
  const int b    = gi0 >> 10;
  const int tid  = threadIdx.x;
  const int lane = tid & 63;
  const int wave = tid >> 6;

  __shared__ float alpha[TI][Nq];   // 32 KB
  __shared__ float xls[TI][Eq];     // 2 KB

  xls[tid >> 6][tid & 63] = xl[(size_t)gi0 * Eq + tid];
  __syncthreads();

  // ---- phase 1: alphaS[r][j] = 1.5*rdot[j] + sum_d att[d]*|xl[r][d]+xr[j][d]| ----
  {
    const int jt = tid & 255;        // 256 j-threads
    const int j0 = jt * 4;
    const int rg = tid >> 8;         // 0/1 -> rows rg*4 .. rg*4+3
    const float4 rd4 = *(const float4*)&rdot[b * Nq + j0];
    const float rdv[4] = {rd4.x, rd4.y, rd4.z, rd4.w};
    float acc[4][4];
#pragma unroll
    for (int rr = 0; rr < 4; ++rr)
#pragma unroll
      for (int jj = 0; jj < 4; ++jj) acc[rr][jj] = 1.5f * rdv[jj];

    const float* __restrict__ xrb = xrT + (size_t)b * Nq + j0;
    for (int ch = 0; ch < 16; ++ch) {
      const float4 av4 = *(const float4*)&att[ch * 4];   // uniform -> s_load
      const float av[4] = {av4.x, av4.y, av4.z, av4.w};
      float xlr[4][4];
#pragma unroll
      for (int rr = 0; rr < 4; ++rr) {
        const float4 v = *(const float4*)&xls[rg * 4 + rr][ch * 4];  // broadcast
        xlr[rr][0] = v.x; xlr[rr][1] = v.y; xlr[rr][2] = v.z; xlr[rr][3] = v.w;
      }
#pragma unroll
      for (int dd = 0; dd < 4; ++dd) {
        const float4 xv4 = *(const float4*)&xrb[(size_t)(ch * 4 + dd) * (Bq * Nq)];
        const float xv[4] = {xv4.x, xv4.y, xv4.z, xv4.w};
        const float a = av[dd];
#pragma unroll
        for (int rr = 0; rr < 4; ++rr) {
          const float xld = xlr[rr][dd];
#pragma unroll
          for (int jj = 0; jj < 4; ++jj)
            acc[rr][jj] = fmaf(fabsf(xld + xv[jj]), a, acc[rr][jj]);
        }
      }
    }
#pragma unroll
    for (int rr = 0; rr < 4; ++rr)
      *(float4*)&alpha[rg * 4 + rr][j0] =
          make_float4(acc[rr][0], acc[rr][1], acc[rr][2], acc[rr][3]);
  }
  __syncthreads();

  // ---- phase 2: wave w = top-K of row w (j = lane + 64*s), DPP-only reduces ----
  float vals[16];
#pragma unroll
  for (int s = 0; s < 16; ++s) vals[s] = alpha[wave][lane + 64 * s];

  float lv = vals[0];
  int   pk = lane;                      // pk = (s<<6)|lane == j; min pk = min j
#pragma unroll
  for (int s = 1; s < 16; ++s)
    if (vals[s] > lv) { lv = vals[s]; pk = (s << 6) | lane; }

  float m0 = 0.f, ssum = 0.f, myv = 0.f;
  int myi = 0;
#pragma unroll 1
  for (int round = 0; round < Kq; ++round) {
    // 64-lane max of lv -> bv (uniform)
    float m = lv;
    m = fmaxf(m, DPP_F(m, QP_XOR1));
    m = fmaxf(m, DPP_F(m, QP_XOR2));
    m = fmaxf(m, DPP_F(m, ROR4));
    m = fmaxf(m, DPP_F(m, ROR8));
    const float bv = fmaxf(fmaxf(RL_F(m, 0), RL_F(m, 16)),
                           fmaxf(RL_F(m, 32), RL_F(m, 48)));
    // min-j among lanes holding bv (exact lax.top_k tie-break)
    int key = (lv == bv) ? pk : 0x7FFFFFFF;
    key = min(key, DPP_I(key, QP_XOR1));
    key = min(key, DPP_I(key, QP_XOR2));
    key = min(key, DPP_I(key, ROR4));
    key = min(key, DPP_I(key, ROR8));
    const int jsel = min(min(RL_I(key, 0), RL_I(key, 16)),
                         min(RL_I(key, 32), RL_I(key, 48)));
    if (round == 0) m0 = bv;
    ssum += __expf(0.4f * (bv - m0));   // undo the /0.4 scaling here
    if (lane == round) { myv = bv; myi = jsel; }
    // knockout + owner-lane rescan
    if (lane == (jsel & 63)) {
      const int sk = jsel >> 6;
#pragma unroll
      for (int s = 0; s < 16; ++s)
        if (s == sk) vals[s] = NEGF;
      lv = vals[0]; pk = lane;
#pragma unroll
      for (int s = 1; s < 16; ++s)
        if (vals[s] > lv) { lv = vals[s]; pk = (s << 6) | lane; }
    }
  }

  if (lane < Kq) {
    const int gi = gi0 + wave;
    const float p = __expf(0.4f * (myv - m0)) / ssum;
    const int base = gi * Kq + lane;
    out[base]            = (float)gi;              // index_i
    out[BNK + base]      = (float)(b * Nq + myi);  // index_j
    out[2 * BNK + base]  = p;                      // attention
  }
}

extern "C" void kernel_launch(void* const* d_in, const int* in_sizes, int n_in,
                              void* d_out, int out_size, void* d_ws, size_t ws_size,
                              hipStream_t stream) {
  const float* x   = (const float*)d_in[0];
  const float* Wl  = (const float*)d_in[1];
  const float* bl  = (const float*)d_in[2];
  const float* Wr  = (const float*)d_in[3];
  const float* br  = (const float*)d_in[4];
  const float* att = (const float*)d_in[5];
  float* out = (float*)d_out;

  float* xl   = (float*)d_ws;                    // [B*N, E]
  float* xrT  = xl + (size_t)Bq * Nq * Eq;       // [E, B*N]
  float* rdot = xrT + (size_t)Eq * Bq * Nq;      // [B*N]

  proj_kernel<<<(Bq * Nq) / 4, 128, 0, stream>>>(x, Wl, bl, Wr, br, att, xl, xrT, rdot);
  attn_kernel<<<(Bq * Nq) / TI, 512, 0, stream>>>(xl, xrT, rdot, att, out);
}